// Round 3
// baseline (1861.128 us; speedup 1.0000x reference)
//
#include <hip/hip_runtime.h>

typedef unsigned short ushort;
typedef unsigned int uint;
typedef __bf16 bf16_t;
typedef bf16_t bf16x8 __attribute__((ext_vector_type(8)));
typedef float f32x4 __attribute__((ext_vector_type(4)));

#define B_ 2048
#define T_ 512
#define D_ 5
#define H_ 128
#define C_ 10
#define BT 16       // batch rows per block
#define BLK 512     // 8 waves: 4 layer-0 waves + 4 layer-1 waves
#define CH 8        // x-staging chunk (steps)
#define HSTR 136    // h tile row stride in ushorts (128 + 8 pad -> conflict-free frags)
#define XSTR 40     // x chunk row stride in ushorts

// ---- dynamic-LDS layout (ushort offsets) ----
// wi1 (swizzled [kt][n][32]): 65536 ush = 128 KiB
#define WI1OFF 0
#define SA0 65536              // h0 buf 0 (16 x 136)
#define SA1 (SA0 + 2176)       // h0 buf 1
#define SB0 (SA0 + 4352)       // h1 buf 0
#define SB1 (SA0 + 6528)       // h1 buf 1
#define XCHO (SA0 + 8704)      // x chunk ring: 8 slots x 16 x 40 = 5120 ush
#define LDS_USH (XCHO + 5120)  // 79360 ush = 158720 B  (<= 160 KiB)

static __device__ __forceinline__ float b2f(ushort u) {
    return __builtin_bit_cast(float, ((uint)u) << 16);
}
static __device__ __forceinline__ ushort f2b(float f) {
    uint u = __builtin_bit_cast(uint, f);
    u += 0x7FFFu + ((u >> 16) & 1u);   // RNE
    return (ushort)(u >> 16);
}
// inf-safe: exp->inf => rcp->0 => sigmoid->0/1, tanh->+-1
static __device__ __forceinline__ float sigf(float x) {
    return __builtin_amdgcn_rcpf(1.0f + __expf(-x));
}
static __device__ __forceinline__ float tanhf_(float x) {
    return 1.0f - 2.0f * __builtin_amdgcn_rcpf(1.0f + __expf(2.0f * x));
}
static __device__ __forceinline__ float ldf(const void* p, long i, bool m32) {
    return m32 ? ((const float*)p)[i] : b2f(((const ushort*)p)[i]);
}
static __device__ __forceinline__ bf16x8 ld16(const ushort* p) {
    return __builtin_bit_cast(bf16x8, *(const uint4*)p);
}
static __device__ __forceinline__ bf16x8 ldfrag(const void* p, long idx, bool m32) {
    if (!m32) return ld16((const ushort*)p + idx);
    const float* f = (const float*)p + idx;
    union { ushort u[8]; bf16x8 v; } r;
#pragma unroll
    for (int j = 0; j < 8; ++j) r.u[j] = f2b(f[j]);
    return r.v;
}
static __device__ __forceinline__ f32x4 splat4(float v) {
    f32x4 r = {v, v, v, v};
    return r;
}
// lgkm-only barrier: LDS exchange without draining global loads in flight
static __device__ __forceinline__ void bar_lds() {
    asm volatile("s_waitcnt lgkmcnt(0)" ::: "memory");
    __builtin_amdgcn_s_barrier();
    asm volatile("" ::: "memory");
}

// ---- dtype detector (proven; picks f32 vs bf16)
__global__ void detect_dtype(const ushort* __restrict__ w, int* __restrict__ flag) {
    __shared__ int cnt;
    if (threadIdx.x == 0) cnt = 0;
    __syncthreads();
    int local = 0;
    for (int i = threadIdx.x; i < 16384; i += 256)
        if ((uint)(w[i] & 0x7F80u) >= 0x4180u) ++local;   // |v| >= 16
    atomicAdd(&cnt, local);
    __syncthreads();
    if (threadIdx.x == 0) *flag = (cnt > 512) ? 1 : 0;
}

// =====================================================================
// Fused two-layer LSTM, wave-specialized with a 1-step skew.
//   waves 0-3 : layer 0, time i   (h0(i) = L0(h0(i-1), x(i)))
//   waves 4-7 : layer 1, time i-1 (h1(i-1) = L1(h0(i-1), h1(i-2)))
// h0/h1 double-buffered in LDS; ONE lgkm barrier per iteration.
// wi1 lives in LDS ([kt][n][32] with XOR bank swizzle); wh0/wh1 in regs.
// No global FIFO, no atomics, no fences, no cross-CU coupling.
// =====================================================================
__global__ __launch_bounds__(BLK, 2) void lstm2_fused(
    const void* __restrict__ x,
    const void* __restrict__ wih0, const void* __restrict__ whh0,
    const void* __restrict__ bih0, const void* __restrict__ bhh0,
    const void* __restrict__ wih1, const void* __restrict__ whh1,
    const void* __restrict__ bih1, const void* __restrict__ bhh1,
    const void* __restrict__ cw1, const void* __restrict__ cb1,
    const void* __restrict__ cw2, const void* __restrict__ cb2,
    const int* __restrict__ flag, void* __restrict__ out)
{
    extern __shared__ __align__(16) ushort lds[];

    const bool m32 = (*flag) != 0;
    const int tid  = threadIdx.x;
    const int w    = tid >> 6;
    const int lane = tid & 63;
    const int quad = lane >> 4;
    const int l16  = lane & 15;
    const int bt0  = blockIdx.x * BT;
    const bool isL0 = (w < 4);
    const int  cb   = (w & 3) * 32;     // 32 cells per role-wave

    // ---- zero h0(-1), h1(-1), xch K-padding
    for (int i2 = tid; i2 < 2176; i2 += BLK) { lds[SA1 + i2] = 0; lds[SB1 + i2] = 0; }
    for (int i2 = tid; i2 < 5120; i2 += BLK) lds[XCHO + i2] = 0;

    // ---- stage wi1 into LDS, [kt][n][32] with XOR swizzle (bank-balanced frags)
    for (int f = tid; f < 8192; f += BLK) {
        int n = f >> 4, k0 = (f & 15) << 3;
        bf16x8 v = ldfrag(wih1, (long)n * 128 + k0, m32);
        int us = (k0 >> 5) * 16384 + n * 32 + ((k0 & 31) ^ ((n & 3) << 3));
        *(uint4*)&lds[us] = __builtin_bit_cast(uint4, v);
    }

    // ---- x chunk mapping: elem e = r*40 + tt*5 + d  (640 elems per chunk)
    const int e0 = tid;
    const int r0 = e0 / 40, rem0 = e0 - r0 * 40;
    const int tt0 = rem0 / 5, d0 = rem0 - tt0 * 5;
    const long xo0 = (long)(bt0 + r0) * T_ * D_ + (long)tt0 * D_ + d0;
    const int xdst0 = (tt0 * 16 + r0) * XSTR + d0;
    const int e1 = tid + 512;
    const int r1 = e1 / 40, rem1 = e1 - r1 * 40;
    const int tt1 = rem1 / 5, d1 = rem1 - tt1 * 5;
    const long xo1 = (long)(bt0 + r1) * T_ * D_ + (long)tt1 * D_ + d1;
    const int xdst1 = (tt1 * 16 + r1) * XSTR + d1;
    const bool has1 = (tid < 128);

    // ---- per-role weight registers
    bf16x8 wreg[2][4][4];   // L0: whh0 frags ; L1: whh1 frags
    bf16x8 xbf[2][4];       // L0 only: wih0 (K=32-padded, quad0 lanes)
    float  bv[2][4];
    int    ibase[2][4];     // L1 only: wi1 LDS frag bases (per nt,g; + kt*16384)
#pragma unroll
    for (int nt = 0; nt < 2; ++nt)
#pragma unroll
        for (int g = 0; g < 4; ++g) {
            const int n = g * 128 + cb + nt * 16 + l16;
            if (isL0) {
#pragma unroll
                for (int kt = 0; kt < 4; ++kt)
                    wreg[nt][g][kt] = ldfrag(whh0, (long)n * 128 + kt * 32 + quad * 8, m32);
                union { ushort u[8]; bf16x8 v; } xt;
#pragma unroll
                for (int j = 0; j < 8; ++j) xt.u[j] = 0;
                if (quad == 0) {
#pragma unroll
                    for (int j = 0; j < 5; ++j)
                        xt.u[j] = f2b(ldf(wih0, (long)n * D_ + j, m32));
                }
                xbf[nt][g] = xt.v;
                bv[nt][g] = ldf(bih0, n, m32) + ldf(bhh0, n, m32);
                ibase[nt][g] = 0;
            } else {
#pragma unroll
                for (int kt = 0; kt < 4; ++kt)
                    wreg[nt][g][kt] = ldfrag(whh1, (long)n * 128 + kt * 32 + quad * 8, m32);
                bv[nt][g] = ldf(bih1, n, m32) + ldf(bhh1, n, m32);
                ibase[nt][g] = n * 32 + ((quad * 8) ^ ((l16 & 3) << 3));
            }
        }
    __syncthreads();   // zeros + wi1 staging complete

    // ---- x chunk 0 -> LDS, chunk 1 -> prefetch regs
    {
        float v0 = ldf(x, xo0, m32);
        lds[XCHO + xdst0] = f2b(v0);
        if (has1) { float v1 = ldf(x, xo1, m32); lds[XCHO + xdst1] = f2b(v1); }
    }
    float xp0 = ldf(x, xo0 + (long)(CH * D_), m32);
    float xp1 = has1 ? ldf(x, xo1 + (long)(CH * D_), m32) : 0.f;
    __syncthreads();   // chunk 0 visible

    f32x4 cst[2];      // cell state per nt (f32x4 over r)
    cst[0] = splat4(0.f);
    cst[1] = splat4(0.f);

#pragma unroll 1
    for (int i = 0; i <= T_; ++i) {
        const int pb = i & 1;
        // x chunk boundary: write prefetched chunk, barrier, prefetch next
        if (i > 0 && i < T_ && (i & (CH - 1)) == 0) {
            lds[XCHO + xdst0] = f2b(xp0);
            if (has1) lds[XCHO + xdst1] = f2b(xp1);
            bar_lds();
            const int tb = i + CH;
            xp0 = (tb + tt0 < T_) ? ldf(x, xo0 + (long)tb * D_, m32) : 0.f;
            xp1 = (has1 && tb + tt1 < T_) ? ldf(x, xo1 + (long)tb * D_, m32) : 0.f;
        }
        const int rdA = pb ? SA0 : SA1;   // h0(i-1)
        if (isL0) {
            if (i < T_) {
                bf16x8 hf[4];
#pragma unroll
                for (int kt = 0; kt < 4; ++kt)
                    hf[kt] = ld16(&lds[rdA + l16 * HSTR + kt * 32 + quad * 8]);
                bf16x8 xa = ld16(&lds[XCHO + ((i & 7) * 16 + l16) * XSTR + quad * 8]);
                f32x4 a[2][4];
#pragma unroll
                for (int nt = 0; nt < 2; ++nt)
#pragma unroll
                    for (int g = 0; g < 4; ++g) {
                        a[nt][g] = splat4(bv[nt][g]);
                        a[nt][g] = __builtin_amdgcn_mfma_f32_16x16x32_bf16(
                            xa, xbf[nt][g], a[nt][g], 0, 0, 0);
                    }
#pragma unroll
                for (int kt = 0; kt < 4; ++kt)
#pragma unroll
                    for (int nt = 0; nt < 2; ++nt)
#pragma unroll
                        for (int g = 0; g < 4; ++g)
                            a[nt][g] = __builtin_amdgcn_mfma_f32_16x16x32_bf16(
                                hf[kt], wreg[nt][g][kt], a[nt][g], 0, 0, 0);
                const int wrA = pb ? SA1 : SA0;
#pragma unroll
                for (int nt = 0; nt < 2; ++nt)
#pragma unroll
                    for (int r = 0; r < 4; ++r) {
                        float iv = sigf(a[nt][0][r]), fv = sigf(a[nt][1][r]);
                        float gv = tanhf_(a[nt][2][r]), ov = sigf(a[nt][3][r]);
                        float cv = fv * cst[nt][r] + iv * gv;
                        cst[nt][r] = cv;
                        lds[wrA + (quad * 4 + r) * HSTR + cb + nt * 16 + l16] =
                            f2b(ov * tanhf_(cv));
                    }
            }
        } else {
            if (i >= 1) {
                const int rdB = pb ? SB1 : SB0;   // h1(i-2)
                const int wrB = pb ? SB0 : SB1;   // h1(i-1)
                bf16x8 h0a[4], hb[4];
#pragma unroll
                for (int kt = 0; kt < 4; ++kt)
                    h0a[kt] = ld16(&lds[rdA + l16 * HSTR + kt * 32 + quad * 8]);
#pragma unroll
                for (int kt = 0; kt < 4; ++kt)
                    hb[kt] = ld16(&lds[rdB + l16 * HSTR + kt * 32 + quad * 8]);
                f32x4 a[2][4];
#pragma unroll
                for (int nt = 0; nt < 2; ++nt)
#pragma unroll
                    for (int g = 0; g < 4; ++g) a[nt][g] = splat4(bv[nt][g]);
#pragma unroll
                for (int kt = 0; kt < 4; ++kt)
#pragma unroll
                    for (int nt = 0; nt < 2; ++nt)
#pragma unroll
                        for (int g = 0; g < 4; ++g) {
                            bf16x8 wf = ld16(&lds[kt * 16384 + ibase[nt][g]]);
                            a[nt][g] = __builtin_amdgcn_mfma_f32_16x16x32_bf16(
                                h0a[kt], wf, a[nt][g], 0, 0, 0);
                        }
#pragma unroll
                for (int kt = 0; kt < 4; ++kt)
#pragma unroll
                    for (int nt = 0; nt < 2; ++nt)
#pragma unroll
                        for (int g = 0; g < 4; ++g)
                            a[nt][g] = __builtin_amdgcn_mfma_f32_16x16x32_bf16(
                                hb[kt], wreg[nt][g][kt], a[nt][g], 0, 0, 0);
#pragma unroll
                for (int nt = 0; nt < 2; ++nt)
#pragma unroll
                    for (int r = 0; r < 4; ++r) {
                        float iv = sigf(a[nt][0][r]), fv = sigf(a[nt][1][r]);
                        float gv = tanhf_(a[nt][2][r]), ov = sigf(a[nt][3][r]);
                        float cv = fv * cst[nt][r] + iv * gv;
                        cst[nt][r] = cv;
                        lds[wrB + (quad * 4 + r) * HSTR + cb + nt * 16 + l16] =
                            f2b(ov * tanhf_(cv));
                    }
            }
        }
        bar_lds();
    }

    // ================= classifier + outputs =================
    // h1(T-1) lives in sB[1]  (written at i=512: pb=0 -> wrB=SB1)
    float* rs = (float*)&lds[XCHO];    // xch region is dead; reuse as [16][64] f32
    if (tid < 256) {
        int m = tid >> 4, j0 = (tid & 15) * 4;
        float s0 = ldf(cb1, j0, m32), s1 = ldf(cb1, j0 + 1, m32);
        float s2 = ldf(cb1, j0 + 2, m32), s3 = ldf(cb1, j0 + 3, m32);
        const ushort* hr = &lds[SB1 + m * HSTR];
#pragma unroll 4
        for (int k = 0; k < 128; ++k) {
            float hv = b2f(hr[k]);
            s0 += hv * ldf(cw1, (long)j0 * 128 + k, m32);
            s1 += hv * ldf(cw1, (long)(j0 + 1) * 128 + k, m32);
            s2 += hv * ldf(cw1, (long)(j0 + 2) * 128 + k, m32);
            s3 += hv * ldf(cw1, (long)(j0 + 3) * 128 + k, m32);
        }
        rs[m * 64 + j0]     = fmaxf(s0, 0.f);
        rs[m * 64 + j0 + 1] = fmaxf(s1, 0.f);
        rs[m * 64 + j0 + 2] = fmaxf(s2, 0.f);
        rs[m * 64 + j0 + 3] = fmaxf(s3, 0.f);
    }
    __syncthreads();
    if (tid < 160) {
        int m = tid / 10, cc = tid - m * 10;
        float s = ldf(cb2, cc, m32);
#pragma unroll
        for (int j = 0; j < 64; ++j)
            s += rs[m * 64 + j] * ldf(cw2, (long)cc * 64 + j, m32);
        long oi = (long)(bt0 + m) * C_ + cc;
        if (m32) ((float*)out)[oi] = s; else ((ushort*)out)[oi] = f2b(s);
    }
    for (int idx = tid; idx < BT * H_; idx += BLK) {
        int m = idx >> 7, k = idx & 127;
        float v = b2f(lds[SB1 + m * HSTR + k]);
        long oi = (long)B_ * C_ + (long)(bt0 + m) * H_ + k;
        if (m32) ((float*)out)[oi] = v; else ((ushort*)out)[oi] = f2b(v);
    }
}

extern "C" void kernel_launch(void* const* d_in, const int* in_sizes, int n_in,
                              void* d_out, int out_size, void* d_ws, size_t ws_size,
                              hipStream_t stream) {
    (void)in_sizes; (void)n_in; (void)out_size; (void)ws_size;
    int* flag = (int*)d_ws;

    static int attr_done = 0;
    if (!attr_done) {
        (void)hipFuncSetAttribute((const void*)lstm2_fused,
                                  hipFuncAttributeMaxDynamicSharedMemorySize,
                                  LDS_USH * 2);
        attr_done = 1;
    }

    hipLaunchKernelGGL(detect_dtype, dim3(1), dim3(256), 0, stream,
                       (const ushort*)d_in[2], flag);

    hipLaunchKernelGGL(lstm2_fused, dim3(B_ / BT), dim3(BLK), LDS_USH * 2, stream,
                       d_in[0], d_in[1], d_in[2], d_in[3], d_in[4],
                       d_in[5], d_in[6], d_in[7], d_in[8],
                       d_in[9], d_in[10], d_in[11], d_in[12],
                       (const int*)flag, d_out);
}

// Round 4
// 1182.192 us; speedup vs baseline: 1.5743x; 1.5743x over previous
//
#include <hip/hip_runtime.h>

typedef unsigned short ushort;
typedef unsigned int uint;
typedef __bf16 bf16_t;
typedef bf16_t bf16x8 __attribute__((ext_vector_type(8)));
typedef float f32x4 __attribute__((ext_vector_type(4)));

#define B_ 2048
#define T_ 512
#define D_ 5
#define H_ 128
#define C_ 10
#define BT 8        // batch rows per block (grid = 256 = one block per CU)
#define BLK 512     // 8 waves, 2 waves/SIMD
#define HSTR 136    // h tile row stride in ushorts (8 rows live)
#define XSTR 20     // x ring row stride in ushorts (16 K-cols + pad)

// ---- dynamic-LDS layout (ushort offsets) ----
#define WI1O 0                 // wi1 frag-linear: 8 waves x 16 frags x 512 ush = 65536
#define A0O  65536             // h0 buf 0: 8 x HSTR = 1088 ush
#define A1O  (A0O + 1088)
#define B0O  (A0O + 2176)      // h1 bufs
#define B1O  (A0O + 3264)
#define XCO  (A0O + 4352)      // x ring: 16 slots x 8 rows x XSTR = 2560 ush
#define LDSU (XCO + 2560)      // 72448 ush = 144896 B (<= 160 KiB)

static __device__ __forceinline__ float b2f(ushort u) {
    return __builtin_bit_cast(float, ((uint)u) << 16);
}
static __device__ __forceinline__ ushort f2b(float f) {
    uint u = __builtin_bit_cast(uint, f);
    u += 0x7FFFu + ((u >> 16) & 1u);   // RNE
    return (ushort)(u >> 16);
}
// inf-safe: exp->inf => rcp->0 => sigmoid->0/1, tanh->+-1
static __device__ __forceinline__ float sigf(float x) {
    return __builtin_amdgcn_rcpf(1.0f + __expf(-x));
}
static __device__ __forceinline__ float tanhf_(float x) {
    return 1.0f - 2.0f * __builtin_amdgcn_rcpf(1.0f + __expf(2.0f * x));
}
static __device__ __forceinline__ float ldf(const void* p, long i, bool m32) {
    return m32 ? ((const float*)p)[i] : b2f(((const ushort*)p)[i]);
}
static __device__ __forceinline__ bf16x8 ld16(const ushort* p) {
    return __builtin_bit_cast(bf16x8, *(const uint4*)p);
}
static __device__ __forceinline__ bf16x8 ldfrag(const void* p, long idx, bool m32) {
    if (!m32) return ld16((const ushort*)p + idx);
    const float* f = (const float*)p + idx;
    union { ushort u[8]; bf16x8 v; } r;
#pragma unroll
    for (int j = 0; j < 8; ++j) r.u[j] = f2b(f[j]);
    return r.v;
}
static __device__ __forceinline__ f32x4 splat4(float v) {
    f32x4 r = {v, v, v, v};
    return r;
}
// lgkm-only barrier: LDS exchange without draining global loads in flight
static __device__ __forceinline__ void bar_lds() {
    asm volatile("s_waitcnt lgkmcnt(0)" ::: "memory");
    __builtin_amdgcn_s_barrier();
    asm volatile("" ::: "memory");
}

// ---- dtype detector (proven; picks f32 vs bf16)
__global__ void detect_dtype(const ushort* __restrict__ w, int* __restrict__ flag) {
    __shared__ int cnt;
    if (threadIdx.x == 0) cnt = 0;
    __syncthreads();
    int local = 0;
    for (int i = threadIdx.x; i < 16384; i += 256)
        if ((uint)(w[i] & 0x7F80u) >= 0x4180u) ++local;   // |v| >= 16
    atomicAdd(&cnt, local);
    __syncthreads();
    if (threadIdx.x == 0) *flag = (cnt > 512) ? 1 : 0;
}

// =====================================================================
// Fully-fused two-layer LSTM, 256 blocks (1/CU), 8 rows/block.
// Within-wave skew: each wave computes L0 gates(t) AND L1 gates(t-1)
// in one MFMA burst (both consume h0(t-1) frags), then one act phase,
// ONE lgkm barrier per step. wi1 in LDS (fragment-linear, conflict-free);
// whh0/whh1 in registers. M=16 tiles carry 8 live rows (quad<2 acts).
// No FIFO, no atomics, no fences, no cross-CU coupling.
// =====================================================================
__global__ __launch_bounds__(BLK, 2) void lstm2_f8(
    const void* __restrict__ x,
    const void* __restrict__ wih0, const void* __restrict__ whh0,
    const void* __restrict__ bih0, const void* __restrict__ bhh0,
    const void* __restrict__ wih1, const void* __restrict__ whh1,
    const void* __restrict__ bih1, const void* __restrict__ bhh1,
    const void* __restrict__ cw1, const void* __restrict__ cb1,
    const void* __restrict__ cw2, const void* __restrict__ cb2,
    const int* __restrict__ flag, void* __restrict__ out)
{
    extern __shared__ __align__(16) ushort lds[];

    const bool m32 = (*flag) != 0;
    const int tid  = threadIdx.x;
    const int w    = tid >> 6;
    const int lane = tid & 63;
    const int quad = lane >> 4;
    const int l16  = lane & 15;
    const int r8   = l16 & 7;            // A-operand row (rows 8-15 duplicate 0-7)
    const int bt0  = blockIdx.x * BT;

    // zero h1(-1) buffer and the x ring (K-padding cols stay zero forever)
    for (int i = tid; i < 1088; i += BLK) lds[B1O + i] = 0;
    for (int i = tid; i < 2560; i += BLK) lds[XCO + i] = 0;

    // ---- weights: whh0/whh1 regs; wih1 -> LDS frag-linear; wih0 regs (quad0/1)
    bf16x8 wh0[4][4], wh1[4][4], xw[4];
    float  b0[4], b1[4];
    const int wfb = WI1O + w * 16 * 512;   // this wave's wi1 frag base
#pragma unroll
    for (int g = 0; g < 4; ++g) {
        const int n = g * 128 + w * 16 + l16;
#pragma unroll
        for (int kt = 0; kt < 4; ++kt) {
            wh0[g][kt] = ldfrag(whh0, (long)n * 128 + kt * 32 + quad * 8, m32);
            wh1[g][kt] = ldfrag(whh1, (long)n * 128 + kt * 32 + quad * 8, m32);
            bf16x8 wi = ldfrag(wih1, (long)n * 128 + kt * 32 + quad * 8, m32);
            *(uint4*)&lds[wfb + (kt * 4 + g) * 512 + lane * 8] =
                __builtin_bit_cast(uint4, wi);
        }
        union { ushort u[8]; bf16x8 v; } xt;
#pragma unroll
        for (int j = 0; j < 8; ++j) xt.u[j] = 0;
        if (quad == 0) {
#pragma unroll
            for (int j = 0; j < 5; ++j) xt.u[j] = f2b(ldf(wih0, (long)n * D_ + j, m32));
        }
        xw[g] = xt.v;
        b0[g] = ldf(bih0, n, m32) + ldf(bhh0, n, m32);
        b1[g] = ldf(bih1, n, m32) + ldf(bhh1, n, m32);
    }

    // ---- x ring staging: 320 elems/chunk (8 rows x 8 steps x 5 d)
    const bool xact = tid < 320;
    const int  e    = xact ? tid : 0;
    const int  rr   = e / 40, rem = e - rr * 40;
    const int  tt   = rem / 5, dd = rem - tt * 5;
    const long xo   = (long)(bt0 + rr) * T_ * D_ + (long)tt * D_ + dd;
    const int  xd   = (tt * 8 + rr) * XSTR + dd;
    if (xact) {
        lds[XCO + xd]             = f2b(ldf(x, xo, m32));             // chunk 0
        lds[XCO + xd + 64 * XSTR] = f2b(ldf(x, xo + 8 * D_, m32));    // chunk 1
    }
    float xp = xact ? ldf(x, xo + 16 * D_, m32) : 0.f;                // chunk 2
    __syncthreads();

    bf16x8 hf0[4], hb1[4];
    {
        uint4 z = make_uint4(0, 0, 0, 0);
#pragma unroll
        for (int kt = 0; kt < 4; ++kt) {
            hf0[kt] = __builtin_bit_cast(bf16x8, z);
            hb1[kt] = __builtin_bit_cast(bf16x8, z);
        }
    }
    bf16x8 xa = ld16(&lds[XCO + (0 * 8 + r8) * XSTR + quad * 8]);

    f32x4 c0 = splat4(0.f), c1 = splat4(0.f);

#pragma unroll 1
    for (int t = 0; t < T_; ++t) {
        // ---------- L0 gates(t) ----------
        f32x4 a0[4];
#pragma unroll
        for (int g = 0; g < 4; ++g) {
            a0[g] = splat4(b0[g]);
            a0[g] = __builtin_amdgcn_mfma_f32_16x16x32_bf16(xa, xw[g], a0[g], 0, 0, 0);
        }
#pragma unroll
        for (int kt = 0; kt < 4; ++kt)
#pragma unroll
            for (int g = 0; g < 4; ++g)
                a0[g] = __builtin_amdgcn_mfma_f32_16x16x32_bf16(
                    hf0[kt], wh0[g][kt], a0[g], 0, 0, 0);

        // x ring refill: write chunk for steps t+8..t+15 (slots not in use)
        if ((t & 7) == 0 && t > 0 && xact)
            lds[XCO + xd + (((t + 8) & 15) >> 3) * 64 * XSTR] = f2b(xp);

        // act L0 -> h0(t)   (frees a0 before L1 accs go live)
        const int wrA = (t & 1) ? A1O : A0O;
        if (quad < 2) {
#pragma unroll
            for (int r = 0; r < 4; ++r) {
                float iv = sigf(a0[0][r]), fv = sigf(a0[1][r]);
                float gv = tanhf_(a0[2][r]), ov = sigf(a0[3][r]);
                float cv = fv * c0[r] + iv * gv;
                c0[r] = cv;
                lds[wrA + (quad * 4 + r) * HSTR + w * 16 + l16] = f2b(ov * tanhf_(cv));
            }
        }

        // ---------- L1 gates(t-1): ih from LDS wi1, hh from regs ----------
        f32x4 a1[4];
#pragma unroll
        for (int g = 0; g < 4; ++g) a1[g] = splat4(b1[g]);
#pragma unroll
        for (int kt = 0; kt < 4; ++kt) {
            bf16x8 wiA = ld16(&lds[wfb + (kt * 4 + 0) * 512 + lane * 8]);
            bf16x8 wiB = ld16(&lds[wfb + (kt * 4 + 1) * 512 + lane * 8]);
            bf16x8 wiC = ld16(&lds[wfb + (kt * 4 + 2) * 512 + lane * 8]);
            bf16x8 wiD = ld16(&lds[wfb + (kt * 4 + 3) * 512 + lane * 8]);
            a1[0] = __builtin_amdgcn_mfma_f32_16x16x32_bf16(hf0[kt], wiA, a1[0], 0, 0, 0);
            a1[1] = __builtin_amdgcn_mfma_f32_16x16x32_bf16(hf0[kt], wiB, a1[1], 0, 0, 0);
            a1[2] = __builtin_amdgcn_mfma_f32_16x16x32_bf16(hf0[kt], wiC, a1[2], 0, 0, 0);
            a1[3] = __builtin_amdgcn_mfma_f32_16x16x32_bf16(hf0[kt], wiD, a1[3], 0, 0, 0);
        }
#pragma unroll
        for (int kt = 0; kt < 4; ++kt)
#pragma unroll
            for (int g = 0; g < 4; ++g)
                a1[g] = __builtin_amdgcn_mfma_f32_16x16x32_bf16(
                    hb1[kt], wh1[g][kt], a1[g], 0, 0, 0);

        // act L1 -> h1(t-1)   (skip at t=0: h1(-1) must stay zero)
        if (t >= 1 && quad < 2) {
            const int wrB = ((t - 1) & 1) ? B1O : B0O;
#pragma unroll
            for (int r = 0; r < 4; ++r) {
                float iv = sigf(a1[0][r]), fv = sigf(a1[1][r]);
                float gv = tanhf_(a1[2][r]), ov = sigf(a1[3][r]);
                float cv = fv * c1[r] + iv * gv;
                c1[r] = cv;
                lds[wrB + (quad * 4 + r) * HSTR + w * 16 + l16] = f2b(ov * tanhf_(cv));
            }
        }

        bar_lds();   // ONE barrier per step

        // next operands: h0(t), h1(t-1), x(t+1)
#pragma unroll
        for (int kt = 0; kt < 4; ++kt)
            hf0[kt] = ld16(&lds[wrA + r8 * HSTR + kt * 32 + quad * 8]);
        const int rdB = ((t - 1) & 1) ? B1O : B0O;   // t=0 -> B1 (zeros)
#pragma unroll
        for (int kt = 0; kt < 4; ++kt)
            hb1[kt] = ld16(&lds[rdB + r8 * HSTR + kt * 32 + quad * 8]);
        xa = ld16(&lds[XCO + (((t + 1) & 15) * 8 + r8) * XSTR + quad * 8]);
        if ((t & 7) == 0 && t > 0) {   // prefetch chunk for steps t+16..t+23
            const int S = t + 16;
            xp = (xact && (S + tt) < T_) ? ldf(x, xo + (long)S * D_, m32) : 0.f;
        }
    }

    // ---------- tail: h1(T-1) ----------
    {
        f32x4 a1[4];
#pragma unroll
        for (int g = 0; g < 4; ++g) a1[g] = splat4(b1[g]);
#pragma unroll
        for (int kt = 0; kt < 4; ++kt) {
            bf16x8 wiA = ld16(&lds[wfb + (kt * 4 + 0) * 512 + lane * 8]);
            bf16x8 wiB = ld16(&lds[wfb + (kt * 4 + 1) * 512 + lane * 8]);
            bf16x8 wiC = ld16(&lds[wfb + (kt * 4 + 2) * 512 + lane * 8]);
            bf16x8 wiD = ld16(&lds[wfb + (kt * 4 + 3) * 512 + lane * 8]);
            a1[0] = __builtin_amdgcn_mfma_f32_16x16x32_bf16(hf0[kt], wiA, a1[0], 0, 0, 0);
            a1[1] = __builtin_amdgcn_mfma_f32_16x16x32_bf16(hf0[kt], wiB, a1[1], 0, 0, 0);
            a1[2] = __builtin_amdgcn_mfma_f32_16x16x32_bf16(hf0[kt], wiC, a1[2], 0, 0, 0);
            a1[3] = __builtin_amdgcn_mfma_f32_16x16x32_bf16(hf0[kt], wiD, a1[3], 0, 0, 0);
        }
#pragma unroll
        for (int kt = 0; kt < 4; ++kt)
#pragma unroll
            for (int g = 0; g < 4; ++g)
                a1[g] = __builtin_amdgcn_mfma_f32_16x16x32_bf16(
                    hb1[kt], wh1[g][kt], a1[g], 0, 0, 0);
        if (quad < 2) {
#pragma unroll
            for (int r = 0; r < 4; ++r) {
                float iv = sigf(a1[0][r]), fv = sigf(a1[1][r]);
                float gv = tanhf_(a1[2][r]), ov = sigf(a1[3][r]);
                float cv = fv * c1[r] + iv * gv;
                c1[r] = cv;
                lds[B1O + (quad * 4 + r) * HSTR + w * 16 + l16] =  // (T-1)&1 = 1
                    f2b(ov * tanhf_(cv));
            }
        }
    }
    __syncthreads();

    // ---------- classifier + outputs (h1(T-1) in B1) ----------
    float* rs = (float*)&lds[XCO];   // x ring dead; reuse as [8][64] f32
    if (tid < 128) {
        int m = tid >> 4, j0 = (tid & 15) * 4;
        float s0 = ldf(cb1, j0, m32), s1 = ldf(cb1, j0 + 1, m32);
        float s2 = ldf(cb1, j0 + 2, m32), s3 = ldf(cb1, j0 + 3, m32);
        const ushort* hr = &lds[B1O + m * HSTR];
#pragma unroll 4
        for (int k = 0; k < 128; ++k) {
            float hv = b2f(hr[k]);
            s0 += hv * ldf(cw1, (long)j0 * 128 + k, m32);
            s1 += hv * ldf(cw1, (long)(j0 + 1) * 128 + k, m32);
            s2 += hv * ldf(cw1, (long)(j0 + 2) * 128 + k, m32);
            s3 += hv * ldf(cw1, (long)(j0 + 3) * 128 + k, m32);
        }
        rs[m * 64 + j0]     = fmaxf(s0, 0.f);
        rs[m * 64 + j0 + 1] = fmaxf(s1, 0.f);
        rs[m * 64 + j0 + 2] = fmaxf(s2, 0.f);
        rs[m * 64 + j0 + 3] = fmaxf(s3, 0.f);
    }
    __syncthreads();
    if (tid < 80) {
        int m = tid / 10, cc = tid - m * 10;
        float s = ldf(cb2, cc, m32);
#pragma unroll
        for (int j = 0; j < 64; ++j)
            s += rs[m * 64 + j] * ldf(cw2, (long)cc * 64 + j, m32);
        long oi = (long)(bt0 + m) * C_ + cc;
        if (m32) ((float*)out)[oi] = s; else ((ushort*)out)[oi] = f2b(s);
    }
    for (int idx = tid; idx < BT * H_; idx += BLK) {
        int m = idx >> 7, k = idx & 127;
        float v = b2f(lds[B1O + m * HSTR + k]);
        long oi = (long)B_ * C_ + (long)(bt0 + m) * H_ + k;
        if (m32) ((float*)out)[oi] = v; else ((ushort*)out)[oi] = f2b(v);
    }
}

extern "C" void kernel_launch(void* const* d_in, const int* in_sizes, int n_in,
                              void* d_out, int out_size, void* d_ws, size_t ws_size,
                              hipStream_t stream) {
    (void)in_sizes; (void)n_in; (void)out_size; (void)ws_size;
    int* flag = (int*)d_ws;

    static int attr_done = 0;
    if (!attr_done) {
        (void)hipFuncSetAttribute((const void*)lstm2_f8,
                                  hipFuncAttributeMaxDynamicSharedMemorySize,
                                  LDSU * 2);
        attr_done = 1;
    }

    hipLaunchKernelGGL(detect_dtype, dim3(1), dim3(256), 0, stream,
                       (const ushort*)d_in[2], flag);

    hipLaunchKernelGGL(lstm2_f8, dim3(B_ / BT), dim3(BLK), LDSU * 2, stream,
                       d_in[0], d_in[1], d_in[2], d_in[3], d_in[4],
                       d_in[5], d_in[6], d_in[7], d_in[8],
                       d_in[9], d_in[10], d_in[11], d_in[12],
                       (const int*)flag, d_out);
}

// Round 7
// 1124.613 us; speedup vs baseline: 1.6549x; 1.0512x over previous
//
#include <hip/hip_runtime.h>

typedef unsigned short ushort;
typedef unsigned int uint;
typedef __bf16 bf16_t;
typedef bf16_t bf16x8 __attribute__((ext_vector_type(8)));
typedef float f32x4 __attribute__((ext_vector_type(4)));

#define B_ 2048
#define T_ 512
#define D_ 5
#define H_ 128
#define C_ 10
#define BT 8        // batch rows per block (grid = 256 = one block per CU)
#define BLK 512     // 8 waves, 2 waves/SIMD
#define HSTR 136    // h tile row stride in ushorts (8 live rows, 16B-aligned)

// ---- dynamic-LDS layout (ushort offsets) ----
#define WI1O 0                  // wi1 frag-linear: 8 waves x 16 frags x 512 = 65536
#define A0O  65536              // h0 bufs x4 (pairs): 4 x 8 x HSTR = 4352
#define B1EO (A0O + 4352)       // h1 even-step buf: 1088
#define B1OO (B1EO + 1088)      // h1 odd-step buf: 1088
#define ZRO  (B1OO + 1088)      // zero row: 136 (masked A-frag rows land here)
#define XCO  (ZRO + 136)        // x ring: 16 slots x 8 rows x 8 ush + 32 pad = 1056
#define LDSU (XCO + 1056)       // 73256 ush = 146512 B (<= 160 KiB)

static __device__ __forceinline__ float b2f(ushort u) {
    return __builtin_bit_cast(float, ((uint)u) << 16);
}
static __device__ __forceinline__ ushort f2b(float f) {
    uint u = __builtin_bit_cast(uint, f);
    u += 0x7FFFu + ((u >> 16) & 1u);   // RNE
    return (ushort)(u >> 16);
}
// inf-safe: exp->inf => rcp->0 => sigmoid->0/1, tanh->+-1
static __device__ __forceinline__ float sigf(float x) {
    return __builtin_amdgcn_rcpf(1.0f + __expf(-x));
}
static __device__ __forceinline__ float tanhf_(float x) {
    return 1.0f - 2.0f * __builtin_amdgcn_rcpf(1.0f + __expf(2.0f * x));
}
static __device__ __forceinline__ float ldf(const void* p, long i, bool m32) {
    return m32 ? ((const float*)p)[i] : b2f(((const ushort*)p)[i]);
}
static __device__ __forceinline__ bf16x8 ld16(const ushort* p) {
    return __builtin_bit_cast(bf16x8, *(const uint4*)p);
}
static __device__ __forceinline__ bf16x8 ldfrag(const void* p, long idx, bool m32) {
    if (!m32) return ld16((const ushort*)p + idx);
    const float* f = (const float*)p + idx;
    union { ushort u[8]; bf16x8 v; } r;
#pragma unroll
    for (int j = 0; j < 8; ++j) r.u[j] = f2b(f[j]);
    return r.v;
}
static __device__ __forceinline__ f32x4 splat4(float v) {
    f32x4 r = {v, v, v, v};
    return r;
}
// lgkm-only barrier: LDS exchange without draining global loads in flight
static __device__ __forceinline__ void bar_lds() {
    asm volatile("s_waitcnt lgkmcnt(0)" ::: "memory");
    __builtin_amdgcn_s_barrier();
    asm volatile("" ::: "memory");
}

// ---- dtype detector (proven; picks f32 vs bf16)
__global__ void detect_dtype(const ushort* __restrict__ w, int* __restrict__ flag) {
    __shared__ int cnt;
    if (threadIdx.x == 0) cnt = 0;
    __syncthreads();
    int local = 0;
    for (int i = threadIdx.x; i < 16384; i += 256)
        if ((uint)(w[i] & 0x7F80u) >= 0x4180u) ++local;   // |v| >= 16
    atomicAdd(&cnt, local);
    __syncthreads();
    if (threadIdx.x == 0) *flag = (cnt > 512) ? 1 : 0;
}

// =====================================================================
// Fully-fused two-layer LSTM, 256 blocks (1/CU), 8 rows/block, 8 waves.
// 2-step batched iteration: L0 computes steps {2I, 2I+1}; L1 LAGS BY 2
// and computes steps {2I-2, 2I-1} (so the batched ih-GEMM consumes only
// h0 values that already exist: rows 0-7 = h0(2I-2), rows 8-15 = h0(2I-1)).
//   - x-GEMM and ih1-GEMM computed ONCE per pair across the 16 M-rows.
//   - recurrent hh-GEMMs per phase with zero-masked A-frags (dead half
//     rows read a zeroed LDS row -> adds exact 0, acc preserved).
//   - cell state alternates quad pairs (even phase: quads 0-1; odd: 2-3),
//     handed across via __shfl_xor(c, 32).
//   - 2 lgkm-only barriers per 2 steps. Final iteration I=256 is L1-only
//     (steps 510, 511). No FIFO/atomics/fences.
// =====================================================================
__global__ __launch_bounds__(BLK, 2) void lstm2_fb(
    const void* __restrict__ x,
    const void* __restrict__ wih0, const void* __restrict__ whh0,
    const void* __restrict__ bih0, const void* __restrict__ bhh0,
    const void* __restrict__ wih1, const void* __restrict__ whh1,
    const void* __restrict__ bih1, const void* __restrict__ bhh1,
    const void* __restrict__ cw1, const void* __restrict__ cb1,
    const void* __restrict__ cw2, const void* __restrict__ cb2,
    const int* __restrict__ flag, void* __restrict__ out)
{
    extern __shared__ __align__(16) ushort lds[];

    const bool m32 = (*flag) != 0;
    const int tid  = threadIdx.x;
    const int w    = tid >> 6;
    const int lane = tid & 63;
    const int quad = lane >> 4;
    const int l16  = lane & 15;
    const int r8   = l16 & 7;
    const bool lo8 = (l16 < 8);
    const int bt0  = blockIdx.x * BT;

    // zero: h0 pair 1 (read at I=0 as h0(-2)/h0(-1)); h1 bufs; ZRO + x ring
    for (int i = tid; i < 2176; i += BLK) {
        lds[A0O + 2176 + i] = 0;
        lds[B1EO + i] = 0;
    }
    for (int i = tid; i < 136 + 1056; i += BLK) lds[ZRO + i] = 0;

    // ---- weights: whh0/whh1 regs; wih1 -> LDS frag-linear; wih0 regs
    bf16x8 wh0[4][4], wh1[4][4], xw[4];
    float  b0[4], b1v[4];
    const int wfb = WI1O + w * 16 * 512;
#pragma unroll
    for (int g = 0; g < 4; ++g) {
        const int n = g * 128 + w * 16 + l16;
#pragma unroll
        for (int kt = 0; kt < 4; ++kt) {
            wh0[g][kt] = ldfrag(whh0, (long)n * 128 + kt * 32 + quad * 8, m32);
            wh1[g][kt] = ldfrag(whh1, (long)n * 128 + kt * 32 + quad * 8, m32);
            bf16x8 wi = ldfrag(wih1, (long)n * 128 + kt * 32 + quad * 8, m32);
            *(uint4*)&lds[wfb + (kt * 4 + g) * 512 + lane * 8] =
                __builtin_bit_cast(uint4, wi);
        }
        union { ushort u[8]; bf16x8 v; } xt;
#pragma unroll
        for (int j = 0; j < 8; ++j) xt.u[j] = 0;
        if (quad == 0) {
#pragma unroll
            for (int j = 0; j < 5; ++j) xt.u[j] = f2b(ldf(wih0, (long)n * D_ + j, m32));
        }
        xw[g] = xt.v;
        b0[g]  = ldf(bih0, n, m32) + ldf(bhh0, n, m32);
        b1v[g] = ldf(bih1, n, m32) + ldf(bhh1, n, m32);
    }

    // ---- x staging: chunk = 8 steps x 8 rows x 5 = 320 elems; slot = 64 ush
    const bool xact = tid < 320;
    const int  e    = xact ? tid : 0;
    const int  rr   = e / 40, rem = e - rr * 40;
    const int  tt   = rem / 5, dd = rem - tt * 5;
    const long xo   = (long)(bt0 + rr) * T_ * D_ + (long)tt * D_ + dd;
    const int  xd   = tt * 64 + rr * 8 + dd;
    if (xact) {
        lds[XCO + xd]       = f2b(ldf(x, xo, m32));            // steps 0-7
        lds[XCO + 512 + xd] = f2b(ldf(x, xo + 8 * D_, m32));   // steps 8-15
    }
    float xp = xact ? ldf(x, xo + 16 * D_, m32) : 0.f;         // steps 16-23
    __syncthreads();

    f32x4 c0 = splat4(0.f), c1 = splat4(0.f);

    // invariant masked h1 A-frag row bases (L1 lag-2 schedule):
    //   even phase (step 2I-2) hh input = h1(2I-3) -> odd buffer, rows 0-7
    //   odd  phase (step 2I-1) hh input = h1(2I-2) -> even buffer, rows 8-15
    const ushort* pH1e = lds + (lo8 ? B1OO + r8 * HSTR : ZRO);
    const ushort* pH1o = lds + (lo8 ? ZRO : B1EO + r8 * HSTR);

#pragma unroll 1
    for (int I = 0; I <= 256; ++I) {
        // x chunk boundary (every 4 iters = 8 steps): write staged chunk, prefetch next
        if ((I & 3) == 0 && I > 0 && I < 256) {
            if (xact) {
                lds[XCO + ((2 * I + 8) & 15) * 64 + xd] = f2b(xp);
                const int S = 2 * I + 16;
                xp = (S + tt < T_) ? ldf(x, xo + (long)S * D_, m32) : 0.f;
            }
        }
        const int s = I & 1;
        const int bIhLo = A0O + (s ^ 1) * 2176;        // h0(2I-2)
        const int bIhHi = bIhLo + 1088;                // h0(2I-1)
        const int bWr0  = A0O + s * 2176;              // h0(2I) write
        const int bWr1  = bWr0 + 1088;                 // h0(2I+1) write
        const ushort* pIh  = lds + (lo8 ? bIhLo + r8 * HSTR : bIhHi + r8 * HSTR);
        const ushort* pH0e = lds + (lo8 ? bIhHi + r8 * HSTR : ZRO);
        const ushort* pH0o = lds + (lo8 ? ZRO : bWr0 + r8 * HSTR);
        const ushort* pXa  = lds + XCO + ((2 * I) & 15) * 64 + l16 * 8 + quad * 8;

        // ===== batched pre-GEMMs: x (L0 both steps) + ih1 (L1 both steps) =====
        f32x4 a0[4], a1[4];
        {
            bf16x8 xaf = ld16(pXa);   // k>=5 junk x zero-weight = 0
#pragma unroll
            for (int g = 0; g < 4; ++g) {
                a0[g] = splat4(b0[g]);
                a0[g] = __builtin_amdgcn_mfma_f32_16x16x32_bf16(xaf, xw[g], a0[g], 0, 0, 0);
                a1[g] = splat4(b1v[g]);
            }
        }
#pragma unroll
        for (int kt = 0; kt < 4; ++kt) {
            bf16x8 ha = ld16(pIh + kt * 32 + quad * 8);
#pragma unroll
            for (int g = 0; g < 4; ++g) {
                bf16x8 wi = ld16(&lds[wfb + (kt * 4 + g) * 512 + lane * 8]);
                a1[g] = __builtin_amdgcn_mfma_f32_16x16x32_bf16(ha, wi, a1[g], 0, 0, 0);
            }
        }
        // ===== even-phase hh (C rows 0-7; rows 8-15 add exact zero) =====
#pragma unroll
        for (int kt = 0; kt < 4; ++kt) {
            bf16x8 he = ld16(pH0e + kt * 32 + quad * 8);
#pragma unroll
            for (int g = 0; g < 4; ++g)
                a0[g] = __builtin_amdgcn_mfma_f32_16x16x32_bf16(
                    he, wh0[g][kt], a0[g], 0, 0, 0);
        }
#pragma unroll
        for (int kt = 0; kt < 4; ++kt) {
            bf16x8 h1e = ld16(pH1e + kt * 32 + quad * 8);
#pragma unroll
            for (int g = 0; g < 4; ++g)
                a1[g] = __builtin_amdgcn_mfma_f32_16x16x32_bf16(
                    h1e, wh1[g][kt], a1[g], 0, 0, 0);
        }
        // ===== even acts =====
        if (I < 256) {   // L0 step 2I -> h0(2I)  (quads 0,1 hold valid rows)
            f32x4 cp;
#pragma unroll
            for (int r = 0; r < 4; ++r) cp[r] = __shfl_xor(c0[r], 32);
#pragma unroll
            for (int r = 0; r < 4; ++r) {
                float iv = sigf(a0[0][r]), fv = sigf(a0[1][r]);
                float gv = tanhf_(a0[2][r]), ov = sigf(a0[3][r]);
                float cv = fv * cp[r] + iv * gv;
                c0[r] = cv;
                ushort hv = f2b(ov * tanhf_(cv));
                if (quad < 2)
                    lds[bWr0 + (quad * 4 + r) * HSTR + w * 16 + l16] = hv;
            }
        }
        if (I > 0) {     // L1 step 2I-2 -> h1(2I-2) into EVEN buffer
            f32x4 cq;
#pragma unroll
            for (int r = 0; r < 4; ++r) cq[r] = __shfl_xor(c1[r], 32);
#pragma unroll
            for (int r = 0; r < 4; ++r) {
                float iv = sigf(a1[0][r]), fv = sigf(a1[1][r]);
                float gv = tanhf_(a1[2][r]), ov = sigf(a1[3][r]);
                float cv = fv * cq[r] + iv * gv;
                c1[r] = cv;
                ushort hv = f2b(ov * tanhf_(cv));
                if (quad < 2)
                    lds[B1EO + (quad * 4 + r) * HSTR + w * 16 + l16] = hv;
            }
        }
        bar_lds();   // mid barrier: h0(2I), h1(2I-2) visible

        // ===== odd-phase hh (C rows 8-15; rows 0-7 add exact zero) =====
#pragma unroll
        for (int kt = 0; kt < 4; ++kt) {
            bf16x8 ho = ld16(pH0o + kt * 32 + quad * 8);
#pragma unroll
            for (int g = 0; g < 4; ++g)
                a0[g] = __builtin_amdgcn_mfma_f32_16x16x32_bf16(
                    ho, wh0[g][kt], a0[g], 0, 0, 0);
        }
#pragma unroll
        for (int kt = 0; kt < 4; ++kt) {
            bf16x8 h1o = ld16(pH1o + kt * 32 + quad * 8);
#pragma unroll
            for (int g = 0; g < 4; ++g)
                a1[g] = __builtin_amdgcn_mfma_f32_16x16x32_bf16(
                    h1o, wh1[g][kt], a1[g], 0, 0, 0);
        }
        // ===== odd acts (quads 2,3 hold valid rows 8-15) =====
        if (I < 256) {   // L0 step 2I+1 -> h0(2I+1)
            f32x4 cp;
#pragma unroll
            for (int r = 0; r < 4; ++r) cp[r] = __shfl_xor(c0[r], 32);
#pragma unroll
            for (int r = 0; r < 4; ++r) {
                float iv = sigf(a0[0][r]), fv = sigf(a0[1][r]);
                float gv = tanhf_(a0[2][r]), ov = sigf(a0[3][r]);
                float cv = fv * cp[r] + iv * gv;
                c0[r] = cv;
                ushort hv = f2b(ov * tanhf_(cv));
                if (quad >= 2)
                    lds[bWr1 + ((quad - 2) * 4 + r) * HSTR + w * 16 + l16] = hv;
            }
        }
        if (I > 0) {     // L1 step 2I-1 -> h1(2I-1) into ODD buffer
            f32x4 cq;
#pragma unroll
            for (int r = 0; r < 4; ++r) cq[r] = __shfl_xor(c1[r], 32);
#pragma unroll
            for (int r = 0; r < 4; ++r) {
                float iv = sigf(a1[0][r]), fv = sigf(a1[1][r]);
                float gv = tanhf_(a1[2][r]), ov = sigf(a1[3][r]);
                float cv = fv * cq[r] + iv * gv;
                c1[r] = cv;
                ushort hv = f2b(ov * tanhf_(cv));
                if (quad >= 2)
                    lds[B1OO + ((quad - 2) * 4 + r) * HSTR + w * 16 + l16] = hv;
            }
        }
        bar_lds();   // end barrier
    }
    __syncthreads();

    // ---------- classifier + outputs (h1(511) in B1OO rows 0-7) ----------
    float* rs = (float*)&lds[XCO];   // x ring dead; reuse as [8][64] f32
    if (tid < 128) {
        int m = tid >> 4, j0 = (tid & 15) * 4;
        float s0 = ldf(cb1, j0, m32), s1 = ldf(cb1, j0 + 1, m32);
        float s2 = ldf(cb1, j0 + 2, m32), s3 = ldf(cb1, j0 + 3, m32);
        const ushort* hr = &lds[B1OO + m * HSTR];
#pragma unroll 4
        for (int k = 0; k < 128; ++k) {
            float hv = b2f(hr[k]);
            s0 += hv * ldf(cw1, (long)j0 * 128 + k, m32);
            s1 += hv * ldf(cw1, (long)(j0 + 1) * 128 + k, m32);
            s2 += hv * ldf(cw1, (long)(j0 + 2) * 128 + k, m32);
            s3 += hv * ldf(cw1, (long)(j0 + 3) * 128 + k, m32);
        }
        rs[m * 64 + j0]     = fmaxf(s0, 0.f);
        rs[m * 64 + j0 + 1] = fmaxf(s1, 0.f);
        rs[m * 64 + j0 + 2] = fmaxf(s2, 0.f);
        rs[m * 64 + j0 + 3] = fmaxf(s3, 0.f);
    }
    __syncthreads();
    if (tid < 80) {
        int m = tid / 10, cc = tid - m * 10;
        float s = ldf(cb2, cc, m32);
#pragma unroll
        for (int j = 0; j < 64; ++j)
            s += rs[m * 64 + j] * ldf(cw2, (long)cc * 64 + j, m32);
        long oi = (long)(bt0 + m) * C_ + cc;
        if (m32) ((float*)out)[oi] = s; else ((ushort*)out)[oi] = f2b(s);
    }
    for (int idx = tid; idx < BT * H_; idx += BLK) {
        int m = idx >> 7, k = idx & 127;
        float v = b2f(lds[B1OO + m * HSTR + k]);
        long oi = (long)B_ * C_ + (long)(bt0 + m) * H_ + k;
        if (m32) ((float*)out)[oi] = v; else ((ushort*)out)[oi] = f2b(v);
    }
}

extern "C" void kernel_launch(void* const* d_in, const int* in_sizes, int n_in,
                              void* d_out, int out_size, void* d_ws, size_t ws_size,
                              hipStream_t stream) {
    (void)in_sizes; (void)n_in; (void)out_size; (void)ws_size;
    int* flag = (int*)d_ws;

    static int attr_done = 0;
    if (!attr_done) {
        (void)hipFuncSetAttribute((const void*)lstm2_fb,
                                  hipFuncAttributeMaxDynamicSharedMemorySize,
                                  LDSU * 2);
        attr_done = 1;
    }

    hipLaunchKernelGGL(detect_dtype, dim3(1), dim3(256), 0, stream,
                       (const ushort*)d_in[2], flag);

    hipLaunchKernelGGL(lstm2_fb, dim3(B_ / BT), dim3(BLK), LDSU * 2, stream,
                       d_in[0], d_in[1], d_in[2], d_in[3], d_in[4],
                       d_in[5], d_in[6], d_in[7], d_in[8],
                       d_in[9], d_in[10], d_in[11], d_in[12],
                       (const int*)flag, d_out);
}